// Round 1
// baseline (553.248 us; speedup 1.0000x reference)
//
#include <hip/hip_runtime.h>
#include <math.h>

#define NUM_TAGS 20000
#define BATCH 64
#define H4 1024
#define HD 256
#define NT1 20001   // NUM_TAGS + 1

__device__ __forceinline__ float gelu_exact(float x) {
    return 0.5f * x * (1.0f + erff(x * 0.7071067811865476f));
}

// ---- async global->LDS (gfx950). LDS dest = wave-uniform base + lane*size.
typedef const __attribute__((address_space(1))) void* gp_t;
typedef __attribute__((address_space(3))) void* lp_t;
__device__ __forceinline__ void async_ld4(const float* g, float* lds_base) {
    __builtin_amdgcn_global_load_lds((gp_t)g, (lp_t)lds_base, 4, 0, 0);
}
__device__ __forceinline__ void async_ld16(const float* g, float* lds_base) {
    __builtin_amdgcn_global_load_lds((gp_t)g, (lp_t)lds_base, 16, 0, 0);
}

// ---------------- counts: scatter with per-(b,f) dedup ----------------
__global__ __launch_bounds__(256) void k_scatter(const int* __restrict__ tags,
                                                 int* __restrict__ counts) {
    int g = blockIdx.x * 256 + threadIdx.x;  // (b,f)
    int b = g >> 7;
    const int* tp = tags + ((size_t)g << 4);
    int t[16];
#pragma unroll
    for (int i = 0; i < 16; ++i) t[i] = tp[i];
#pragma unroll
    for (int i = 0; i < 16; ++i) {
        bool dup = false;
        for (int j = 0; j < i; ++j) dup = dup || (t[j] == t[i]);
        if (!dup) atomicAdd(&counts[(size_t)b * NUM_TAGS + t[i]], 1);
    }
}

// ---------------- LN1 phase A: partial stats ----------------
__global__ __launch_bounds__(256) void k_ln1_stats(const int* __restrict__ counts,
                                                   float* __restrict__ stats) {
    int b = blockIdx.y, c = blockIdx.x, tid = threadIdx.x;
    const int* crow = counts + (size_t)b * NUM_TAGS;
    int lo = c * 2500, hi = lo + 2500;
    float s = 0.f, s2 = 0.f;
    for (int t = lo + tid; t < hi; t += 256) {
        float v = (float)crow[t];
        s += v; s2 += v * v;
    }
#pragma unroll
    for (int off = 32; off > 0; off >>= 1) {
        s  += __shfl_down(s, off);
        s2 += __shfl_down(s2, off);
    }
    __shared__ float ls[4], ls2[4];
    int wave = tid >> 6;
    if ((tid & 63) == 0) { ls[wave] = s; ls2[wave] = s2; }
    __syncthreads();
    if (tid == 0) {
        stats[(b * 8 + c) * 2 + 0] = ls[0] + ls[1] + ls[2] + ls[3];
        stats[(b * 8 + c) * 2 + 1] = ls2[0] + ls2[1] + ls2[2] + ls2[3];
    }
}

// ---------------- LN1 phase B: apply ----------------
__global__ __launch_bounds__(256) void k_ln1_apply(const int* __restrict__ counts,
                                                   const float* __restrict__ fc,
                                                   const float* __restrict__ lng,
                                                   const float* __restrict__ lnb,
                                                   const float* __restrict__ stats,
                                                   float* __restrict__ y) {
    int b = blockIdx.y, c = blockIdx.x, tid = threadIdx.x;
    float S = 0.f, S2 = 0.f;
#pragma unroll
    for (int i = 0; i < 8; ++i) {
        S  += stats[(b * 8 + i) * 2 + 0];
        S2 += stats[(b * 8 + i) * 2 + 1];
    }
    float mu = S / (float)NUM_TAGS;
    float var = S2 / (float)NUM_TAGS - mu * mu;
    float rs = rsqrtf(var + 1e-5f);
    const int* crow = counts + (size_t)b * NUM_TAGS;
    float* yrow = y + (size_t)b * NT1;
    if (c == 0 && tid == 0) yrow[0] = fc[b] * 0.01f;
    int lo = c * 2500, hi = lo + 2500;
    for (int t = lo + tid; t < hi; t += 256) {
        float v = (float)crow[t];
        yrow[1 + t] = (v - mu) * rs * lng[t] + lnb[t];
    }
}

// ---------------- async 4-buffer deep-pipelined split-K GEMM ----------------
// P[(bx*KS+ky)][64][256] = A[64, kslice] @ W[kslice, 256cols]
// 256 thr: tn=tid&31 (cols tn*4..+3 and 128+tn*4..+3), tb=tid>>5 (8 rows each).
// BK=8, 4 LDS buffers, depth-2 prefetch, counted vmcnt (no full drain in loop).
// Requires: kpb % 8 == 0, all K-slices full.
// PATH 0: W rows 16B-aligned (ldw%4==0, N%256==0). PATH 1: dword W loads,
// col clamped to N-1 (odd ldw ok).
// Loads per thread per chunk L: PATH0 = 2(A)+2(W16) = 4; PATH1 = 2(A)+8(W4) = 10.
template <int PATH>
__global__ __launch_bounds__(256, 4) void k_gemm(const float* __restrict__ A, int lda,
                                                 const float* __restrict__ W, int ldw,
                                                 float* __restrict__ P,
                                                 int N, int kpb) {
    __shared__ __align__(16) float As[4][512];    // [row][kk] : row*8 + kk
    __shared__ __align__(16) float Ws[4][2048];   // [kk][col] : kk*256 + col
    const int tid = threadIdx.x;
    const int lane = tid & 63, wid = tid >> 6;
    const int tn = tid & 31, tb = tid >> 5;
    const int n0 = blockIdx.x * 256;
    const int kstart = blockIdx.y * kpb;
    const int nchunk = kpb >> 3;

    float acc[8][8];
#pragma unroll
    for (int i = 0; i < 8; ++i)
#pragma unroll
        for (int j = 0; j < 8; ++j) acc[i][j] = 0.f;

    // ---- issue chunk c into buffer b (async DMA) ----
    auto issue = [&](int b, int c) {
        int k0 = kstart + c * 8;
        // A tile: 64x8 = 512 dwords; d -> row=d>>3, kk=d&7
#pragma unroll
        for (int j = 0; j < 2; ++j) {
            int d0 = j * 256 + wid * 64;
            int d = d0 + lane;
            async_ld4(A + (size_t)(d >> 3) * lda + k0 + (d & 7), &As[b][d0]);
        }
        if (PATH == 0) {
            // W tile: 8 rows x 256 cols = 512 16B-granules; g -> kk=g>>6, c4=g&63
#pragma unroll
            for (int j = 0; j < 2; ++j) {
                int g0 = j * 256 + wid * 64;
                int g = g0 + lane;
                int kk = g >> 6, c4 = g & 63;
                async_ld16(W + (size_t)(k0 + kk) * ldw + n0 + c4 * 4, &Ws[b][g0 * 4]);
            }
        } else {
            // W tile: 2048 dwords; d -> kk=d>>8, c=d&255 (col clamped)
#pragma unroll
            for (int j = 0; j < 8; ++j) {
                int d0 = j * 256 + wid * 64;
                int d = d0 + lane;
                int kk = d >> 8, cc = d & 255;
                async_ld4(W + (size_t)(k0 + kk) * ldw + min(n0 + cc, N - 1), &Ws[b][d0]);
            }
        }
    };

    issue(0, 0);
    if (nchunk > 1) issue(1, 1);

    for (int c = 0; c < nchunk; ++c) {
        if (c + 2 < nchunk) issue((c + 2) & 3, c + 2);
        // Counted wait: keep up to 2 chunks' loads in flight across the barrier.
        // After this wave's own chunk-c loads retire, <= 2L (or L / 0 at the
        // tail) remain outstanding.
        int ahead = nchunk - 1 - c;
        if (PATH == 0) {
            if (ahead >= 2)      asm volatile("s_waitcnt vmcnt(8)"  ::: "memory");
            else if (ahead == 1) asm volatile("s_waitcnt vmcnt(4)"  ::: "memory");
            else                 asm volatile("s_waitcnt vmcnt(0)"  ::: "memory");
        } else {
            if (ahead >= 2)      asm volatile("s_waitcnt vmcnt(20)" ::: "memory");
            else if (ahead == 1) asm volatile("s_waitcnt vmcnt(10)" ::: "memory");
            else                 asm volatile("s_waitcnt vmcnt(0)"  ::: "memory");
        }
        __builtin_amdgcn_s_barrier();          // all waves' chunk-c loads landed
        asm volatile("" ::: "memory");         // no LDS access hoisted above

        const float* Ab = As[c & 3];
        const float* Wb = Ws[c & 3];
        __builtin_amdgcn_s_setprio(1);
#pragma unroll
        for (int k4 = 0; k4 < 2; ++k4) {
            float4 a4[8];
#pragma unroll
            for (int i = 0; i < 8; ++i)
                a4[i] = *(const float4*)&Ab[(tb * 8 + i) * 8 + k4 * 4];
#pragma unroll
            for (int kl = 0; kl < 4; ++kl) {
                // lane-contiguous 16B reads -> conflict-free
                const float4 w0 = *(const float4*)&Wb[(k4 * 4 + kl) * 256 + tn * 4];
                const float4 w1 = *(const float4*)&Wb[(k4 * 4 + kl) * 256 + 128 + tn * 4];
                const float wv[8] = {w0.x, w0.y, w0.z, w0.w, w1.x, w1.y, w1.z, w1.w};
#pragma unroll
                for (int i = 0; i < 8; ++i) {
                    float av = (kl == 0) ? a4[i].x : (kl == 1) ? a4[i].y
                             : (kl == 2) ? a4[i].z : a4[i].w;
#pragma unroll
                    for (int jj = 0; jj < 8; ++jj)
                        acc[i][jj] = fmaf(av, wv[jj], acc[i][jj]);
                }
            }
        }
        __builtin_amdgcn_s_setprio(0);
        asm volatile("" ::: "memory");         // no LDS access sunk below
    }

    float* Pp = P + ((size_t)blockIdx.x * gridDim.y + blockIdx.y) * 16384;
#pragma unroll
    for (int i = 0; i < 8; ++i) {
        int row = tb * 8 + i;
        float4 v0 = {acc[i][0], acc[i][1], acc[i][2], acc[i][3]};
        float4 v1 = {acc[i][4], acc[i][5], acc[i][6], acc[i][7]};
        *(float4*)&Pp[row * 256 + tn * 4]       = v0;
        *(float4*)&Pp[row * 256 + 128 + tn * 4] = v1;
    }
}

// ---------------- reduce partials + bias (+rank-1 fc term) (+gelu) ---------
template <bool GELU>
__global__ __launch_bounds__(256) void k_reduce(const float* __restrict__ P, int KS,
                                                const float* __restrict__ bias,
                                                const float* __restrict__ r1row,
                                                const float* __restrict__ fc,
                                                float* __restrict__ out, int ldo, int N) {
    int b = blockIdx.y;
    int n = blockIdx.x * 256 + threadIdx.x;
    if (n >= N) return;
    int nb = n >> 8, col = n & 255;
    const float* p = P + (size_t)nb * KS * 16384 + b * 256 + col;
    float s0 = 0.f, s1 = 0.f, s2 = 0.f, s3 = 0.f;
    int k = 0;
    for (; k + 3 < KS; k += 4) {
        s0 += p[(size_t)(k + 0) * 16384];
        s1 += p[(size_t)(k + 1) * 16384];
        s2 += p[(size_t)(k + 2) * 16384];
        s3 += p[(size_t)(k + 3) * 16384];
    }
    for (; k < KS; ++k) s0 += p[(size_t)k * 16384];
    float s = (s0 + s1) + (s2 + s3) + bias[n];
    if (r1row) s += fc[b] * 0.01f * r1row[n];
    if (GELU) s = gelu_exact(s);
    out[(size_t)b * ldo + n] = s;
}

// ---------------- LN2: one block per row (1024 cols) ----------------
__global__ __launch_bounds__(256) void k_ln2(const float* __restrict__ g1,
                                             const float* __restrict__ lng,
                                             const float* __restrict__ lnb,
                                             float* __restrict__ h2) {
    int b = blockIdx.x, tid = threadIdx.x;
    float v[4];
    float s = 0.f, s2 = 0.f;
#pragma unroll
    for (int j = 0; j < 4; ++j) {
        int nidx = tid + 256 * j;
        float x = g1[b * H4 + nidx];
        v[j] = x;
        s += x; s2 += x * x;
    }
#pragma unroll
    for (int off = 32; off > 0; off >>= 1) {
        s  += __shfl_down(s, off);
        s2 += __shfl_down(s2, off);
    }
    __shared__ float ls[4], ls2[4], smu, srs;
    int wave = tid >> 6;
    if ((tid & 63) == 0) { ls[wave] = s; ls2[wave] = s2; }
    __syncthreads();
    if (tid == 0) {
        float S  = ls[0] + ls[1] + ls[2] + ls[3];
        float S2 = ls2[0] + ls2[1] + ls2[2] + ls2[3];
        float mu = S / (float)H4;
        float var = S2 / (float)H4 - mu * mu;
        smu = mu;
        srs = rsqrtf(var + 1e-5f);
    }
    __syncthreads();
    float mu = smu, rs = srs;
#pragma unroll
    for (int j = 0; j < 4; ++j) {
        int nidx = tid + 256 * j;
        h2[b * H4 + nidx] = (v[j] - mu) * rs * lng[nidx] + lnb[nidx];
    }
}

// ---------------- launch ----------------
extern "C" void kernel_launch(void* const* d_in, const int* in_sizes, int n_in,
                              void* d_out, int out_size, void* d_ws, size_t ws_size,
                              hipStream_t stream) {
    (void)in_sizes; (void)n_in; (void)out_size;
    const int*   tags  = (const int*)d_in[0];
    const float* fc    = (const float*)d_in[1];
    const float* ln_g  = (const float*)d_in[2];
    const float* ln_b  = (const float*)d_in[3];
    const float* w1    = (const float*)d_in[4];
    const float* b1    = (const float*)d_in[5];
    const float* ln2_g = (const float*)d_in[6];
    const float* ln2_b = (const float*)d_in[7];
    const float* we1   = (const float*)d_in[8];
    const float* be1   = (const float*)d_in[9];
    const float* we2   = (const float*)d_in[10];
    const float* be2   = (const float*)d_in[11];
    const float* wd1   = (const float*)d_in[12];
    const float* bd1   = (const float*)d_in[13];
    const float* wd2   = (const float*)d_in[14];
    const float* bd2   = (const float*)d_in[15];

    float* out = (float*)d_out;
    float* y   = out;                              // 64*20001
    float* enc = out + (size_t)BATCH * NT1;        // 64*256
    float* dec = enc + BATCH * HD;                 // 64*20001

    char* ws = (char*)d_ws;
    size_t off = 0;
    int*   counts = (int*)(ws + off);   off += (size_t)BATCH * NUM_TAGS * 4;  // 5.12 MB
    float* stats  = (float*)(ws + off); off += 64 * 8 * 2 * 4;
    float* g1     = (float*)(ws + off); off += (size_t)BATCH * H4 * 4;
    float* h2     = (float*)(ws + off); off += (size_t)BATCH * H4 * 4;
    float* g2     = (float*)(ws + off); off += (size_t)BATCH * H4 * 4;
    float* dd     = (float*)(ws + off); off += (size_t)BATCH * H4 * 4;
    float* arena  = (float*)(ws + off);
    size_t avail  = (ws_size > off) ? (ws_size - off) : 0;

    // split-K tiers (ws_size constant across calls -> deterministic)
    const size_t MB = 1024 * 1024;
    int KS1, KS5;
    if (avail >= 45 * MB)      { KS1 = 125; KS5 = 8; }   // arenas 32.8 / 41.4 MB
    else if (avail >= 33 * MB) { KS1 = 125; KS5 = 4; }
    else if (avail >= 17 * MB) { KS1 = 63;  KS5 = 4; }
    else                       { KS1 = 63;  KS5 = 2; }
    int kpb5 = H4 / KS5;
    (void)KS1;

    hipMemsetAsync(counts, 0, (size_t)BATCH * NUM_TAGS * 4, stream);
    k_scatter<<<32, 256, 0, stream>>>(tags, counts);
    k_ln1_stats<<<dim3(8, 64), 256, 0, stream>>>(counts, stats);
    k_ln1_apply<<<dim3(8, 64), 256, 0, stream>>>(counts, fc, ln_g, ln_b, stats, y);

    // GEMM1: yn[64,20000] @ w1[1:,1024]; fc-column folded into reduce as rank-1
    k_gemm<0><<<dim3(4, 125), 256, 0, stream>>>(y + 1, NT1, w1 + H4, H4, arena, H4, 160);
    k_reduce<true><<<dim3(4, 64), 256, 0, stream>>>(arena, 125, b1, w1, fc, g1, H4, H4);
    k_ln2<<<64, 256, 0, stream>>>(g1, ln2_g, ln2_b, h2);

    // GEMM2: h2 @ we1[1024,1024]
    k_gemm<0><<<dim3(4, 32), 256, 0, stream>>>(h2, H4, we1, H4, arena, H4, 32);
    k_reduce<true><<<dim3(4, 64), 256, 0, stream>>>(arena, 32, be1, nullptr, nullptr, g2, H4, H4);

    // GEMM3: g2 @ we2[1024,256]
    k_gemm<0><<<dim3(1, 32), 256, 0, stream>>>(g2, H4, we2, HD, arena, HD, 32);
    k_reduce<false><<<dim3(1, 64), 256, 0, stream>>>(arena, 32, be2, nullptr, nullptr, enc, HD, HD);

    // GEMM4: enc @ wd1[256,1024]
    k_gemm<0><<<dim3(4, 16), 256, 0, stream>>>(enc, HD, wd1, H4, arena, H4, 16);
    k_reduce<true><<<dim3(4, 64), 256, 0, stream>>>(arena, 16, bd1, nullptr, nullptr, dd, H4, H4);

    // GEMM5: dd @ wd2[1024,20001]  (odd ldw -> PATH 1)
    k_gemm<1><<<dim3(79, KS5), 256, 0, stream>>>(dd, H4, wd2, NT1, arena, NT1, kpb5);
    k_reduce<false><<<dim3(79, 64), 256, 0, stream>>>(arena, KS5, bd2, nullptr, nullptr, dec, NT1, NT1);
}

// Round 2
// 330.944 us; speedup vs baseline: 1.6717x; 1.6717x over previous
//
#include <hip/hip_runtime.h>
#include <math.h>

#define NUM_TAGS 20000
#define BATCH 64
#define H4 1024
#define HD 256
#define NT1 20001   // NUM_TAGS + 1

__device__ __forceinline__ float gelu_exact(float x) {
    return 0.5f * x * (1.0f + erff(x * 0.7071067811865476f));
}

// ---- async global->LDS (gfx950). LDS dest = wave-uniform base + lane*size.
typedef const __attribute__((address_space(1))) void* gp_t;
typedef __attribute__((address_space(3))) void* lp_t;
__device__ __forceinline__ void async_ld4(const float* g, float* lds_base) {
    __builtin_amdgcn_global_load_lds((gp_t)g, (lp_t)lds_base, 4, 0, 0);
}
__device__ __forceinline__ void async_ld16(const float* g, float* lds_base) {
    __builtin_amdgcn_global_load_lds((gp_t)g, (lp_t)lds_base, 16, 0, 0);
}

// ---------------- counts: scatter with per-(b,f) dedup ----------------
__global__ __launch_bounds__(256) void k_scatter(const int* __restrict__ tags,
                                                 int* __restrict__ counts) {
    int g = blockIdx.x * 256 + threadIdx.x;  // (b,f)
    int b = g >> 7;
    const int* tp = tags + ((size_t)g << 4);
    int t[16];
#pragma unroll
    for (int i = 0; i < 16; ++i) t[i] = tp[i];
#pragma unroll
    for (int i = 0; i < 16; ++i) {
        bool dup = false;
        for (int j = 0; j < i; ++j) dup = dup || (t[j] == t[i]);
        if (!dup) atomicAdd(&counts[(size_t)b * NUM_TAGS + t[i]], 1);
    }
}

// ---------------- LN1 phase A: partial stats ----------------
__global__ __launch_bounds__(256) void k_ln1_stats(const int* __restrict__ counts,
                                                   float* __restrict__ stats) {
    int b = blockIdx.y, c = blockIdx.x, tid = threadIdx.x;
    const int* crow = counts + (size_t)b * NUM_TAGS;
    int lo = c * 2500, hi = lo + 2500;
    float s = 0.f, s2 = 0.f;
    for (int t = lo + tid; t < hi; t += 256) {
        float v = (float)crow[t];
        s += v; s2 += v * v;
    }
#pragma unroll
    for (int off = 32; off > 0; off >>= 1) {
        s  += __shfl_down(s, off);
        s2 += __shfl_down(s2, off);
    }
    __shared__ float ls[4], ls2[4];
    int wave = tid >> 6;
    if ((tid & 63) == 0) { ls[wave] = s; ls2[wave] = s2; }
    __syncthreads();
    if (tid == 0) {
        stats[(b * 8 + c) * 2 + 0] = ls[0] + ls[1] + ls[2] + ls[3];
        stats[(b * 8 + c) * 2 + 1] = ls2[0] + ls2[1] + ls2[2] + ls2[3];
    }
}

// ---------------- LN1 phase B: apply ----------------
__global__ __launch_bounds__(256) void k_ln1_apply(const int* __restrict__ counts,
                                                   const float* __restrict__ fc,
                                                   const float* __restrict__ lng,
                                                   const float* __restrict__ lnb,
                                                   const float* __restrict__ stats,
                                                   float* __restrict__ y) {
    int b = blockIdx.y, c = blockIdx.x, tid = threadIdx.x;
    float S = 0.f, S2 = 0.f;
#pragma unroll
    for (int i = 0; i < 8; ++i) {
        S  += stats[(b * 8 + i) * 2 + 0];
        S2 += stats[(b * 8 + i) * 2 + 1];
    }
    float mu = S / (float)NUM_TAGS;
    float var = S2 / (float)NUM_TAGS - mu * mu;
    float rs = rsqrtf(var + 1e-5f);
    const int* crow = counts + (size_t)b * NUM_TAGS;
    float* yrow = y + (size_t)b * NT1;
    if (c == 0 && tid == 0) yrow[0] = fc[b] * 0.01f;
    int lo = c * 2500, hi = lo + 2500;
    for (int t = lo + tid; t < hi; t += 256) {
        float v = (float)crow[t];
        yrow[1 + t] = (v - mu) * rs * lng[t] + lnb[t];
    }
}

// ---------------- async 4-buffer deep-pipelined split-K GEMM ----------------
// P[(bx*KS+ky)][64][256] = A[64, kslice] @ W[kslice, 256cols]
// 256 thr: tn=tid&31 (cols tn*4..+3 and 128+tn*4..+3), tb=tid>>5 (8 rows each).
// BK=8, 4 LDS buffers, depth-2 prefetch, counted vmcnt (no full drain in loop).
// Requires: kpb % 8 == 0, all K-slices full.
// PATH 0: W rows 16B-aligned (ldw%4==0, N%256==0). PATH 1: dword W loads,
// col clamped to N-1 (odd ldw ok).
// Loads per thread per chunk L: PATH0 = 2(A)+2(W16) = 4; PATH1 = 2(A)+8(W4) = 10.
// launch_bounds(256,2): empirically 96 VGPR / no spill with this inner loop
// (round-0); (256,4) made the compiler clamp to 64 VGPR -> 94 MB scratch spill.
template <int PATH>
__global__ __launch_bounds__(256, 2) void k_gemm(const float* __restrict__ A, int lda,
                                                 const float* __restrict__ W, int ldw,
                                                 float* __restrict__ P,
                                                 int N, int kpb) {
    __shared__ __align__(16) float As[4][512];    // [row][kk] : row*8 + kk
    __shared__ __align__(16) float Ws[4][2048];   // [kk][col] : kk*256 + col
    const int tid = threadIdx.x;
    const int lane = tid & 63, wid = tid >> 6;
    const int tn = tid & 31, tb = tid >> 5;
    const int n0 = blockIdx.x * 256;
    const int kstart = blockIdx.y * kpb;
    const int nchunk = kpb >> 3;

    float acc[8][8];
#pragma unroll
    for (int i = 0; i < 8; ++i)
#pragma unroll
        for (int j = 0; j < 8; ++j) acc[i][j] = 0.f;

    // ---- issue chunk c into buffer b (async DMA) ----
    auto issue = [&](int b, int c) {
        int k0 = kstart + c * 8;
        // A tile: 64x8 = 512 dwords; d -> row=d>>3, kk=d&7
#pragma unroll
        for (int j = 0; j < 2; ++j) {
            int d0 = j * 256 + wid * 64;
            int d = d0 + lane;
            async_ld4(A + (size_t)(d >> 3) * lda + k0 + (d & 7), &As[b][d0]);
        }
        if (PATH == 0) {
            // W tile: 8 rows x 256 cols = 512 16B-granules; g -> kk=g>>6, c4=g&63
#pragma unroll
            for (int j = 0; j < 2; ++j) {
                int g0 = j * 256 + wid * 64;
                int g = g0 + lane;
                int kk = g >> 6, c4 = g & 63;
                async_ld16(W + (size_t)(k0 + kk) * ldw + n0 + c4 * 4, &Ws[b][g0 * 4]);
            }
        } else {
            // W tile: 2048 dwords; d -> kk=d>>8, c=d&255 (col clamped)
#pragma unroll
            for (int j = 0; j < 8; ++j) {
                int d0 = j * 256 + wid * 64;
                int d = d0 + lane;
                int kk = d >> 8, cc = d & 255;
                async_ld4(W + (size_t)(k0 + kk) * ldw + min(n0 + cc, N - 1), &Ws[b][d0]);
            }
        }
    };

    issue(0, 0);
    if (nchunk > 1) issue(1, 1);

    for (int c = 0; c < nchunk; ++c) {
        if (c + 2 < nchunk) issue((c + 2) & 3, c + 2);
        // Counted wait: keep up to 2 chunks' loads in flight across the barrier.
        // After this wave's own chunk-c loads retire, <= 2L (or L / 0 at the
        // tail) remain outstanding.
        int ahead = nchunk - 1 - c;
        if (PATH == 0) {
            if (ahead >= 2)      asm volatile("s_waitcnt vmcnt(8)"  ::: "memory");
            else if (ahead == 1) asm volatile("s_waitcnt vmcnt(4)"  ::: "memory");
            else                 asm volatile("s_waitcnt vmcnt(0)"  ::: "memory");
        } else {
            if (ahead >= 2)      asm volatile("s_waitcnt vmcnt(20)" ::: "memory");
            else if (ahead == 1) asm volatile("s_waitcnt vmcnt(10)" ::: "memory");
            else                 asm volatile("s_waitcnt vmcnt(0)"  ::: "memory");
        }
        __builtin_amdgcn_s_barrier();          // all waves' chunk-c loads landed
        asm volatile("" ::: "memory");         // no LDS access hoisted above

        const float* Ab = As[c & 3];
        const float* Wb = Ws[c & 3];
        __builtin_amdgcn_s_setprio(1);
#pragma unroll
        for (int k4 = 0; k4 < 2; ++k4) {
            float4 a4[8];
#pragma unroll
            for (int i = 0; i < 8; ++i)
                a4[i] = *(const float4*)&Ab[(tb * 8 + i) * 8 + k4 * 4];
#pragma unroll
            for (int kl = 0; kl < 4; ++kl) {
                // lane-contiguous 16B reads -> conflict-free
                const float4 w0 = *(const float4*)&Wb[(k4 * 4 + kl) * 256 + tn * 4];
                const float4 w1 = *(const float4*)&Wb[(k4 * 4 + kl) * 256 + 128 + tn * 4];
                const float wv[8] = {w0.x, w0.y, w0.z, w0.w, w1.x, w1.y, w1.z, w1.w};
#pragma unroll
                for (int i = 0; i < 8; ++i) {
                    float av = (kl == 0) ? a4[i].x : (kl == 1) ? a4[i].y
                             : (kl == 2) ? a4[i].z : a4[i].w;
#pragma unroll
                    for (int jj = 0; jj < 8; ++jj)
                        acc[i][jj] = fmaf(av, wv[jj], acc[i][jj]);
                }
            }
        }
        __builtin_amdgcn_s_setprio(0);
        asm volatile("" ::: "memory");         // no LDS access sunk below
    }

    float* Pp = P + ((size_t)blockIdx.x * gridDim.y + blockIdx.y) * 16384;
#pragma unroll
    for (int i = 0; i < 8; ++i) {
        int row = tb * 8 + i;
        float4 v0 = {acc[i][0], acc[i][1], acc[i][2], acc[i][3]};
        float4 v1 = {acc[i][4], acc[i][5], acc[i][6], acc[i][7]};
        *(float4*)&Pp[row * 256 + tn * 4]       = v0;
        *(float4*)&Pp[row * 256 + 128 + tn * 4] = v1;
    }
}

// ---------------- reduce partials + bias (+rank-1 fc term) (+gelu) ---------
template <bool GELU>
__global__ __launch_bounds__(256) void k_reduce(const float* __restrict__ P, int KS,
                                                const float* __restrict__ bias,
                                                const float* __restrict__ r1row,
                                                const float* __restrict__ fc,
                                                float* __restrict__ out, int ldo, int N) {
    int b = blockIdx.y;
    int n = blockIdx.x * 256 + threadIdx.x;
    if (n >= N) return;
    int nb = n >> 8, col = n & 255;
    const float* p = P + (size_t)nb * KS * 16384 + b * 256 + col;
    float s0 = 0.f, s1 = 0.f, s2 = 0.f, s3 = 0.f;
    int k = 0;
    for (; k + 3 < KS; k += 4) {
        s0 += p[(size_t)(k + 0) * 16384];
        s1 += p[(size_t)(k + 1) * 16384];
        s2 += p[(size_t)(k + 2) * 16384];
        s3 += p[(size_t)(k + 3) * 16384];
    }
    for (; k < KS; ++k) s0 += p[(size_t)k * 16384];
    float s = (s0 + s1) + (s2 + s3) + bias[n];
    if (r1row) s += fc[b] * 0.01f * r1row[n];
    if (GELU) s = gelu_exact(s);
    out[(size_t)b * ldo + n] = s;
}

// ---------------- LN2: one block per row (1024 cols) ----------------
__global__ __launch_bounds__(256) void k_ln2(const float* __restrict__ g1,
                                             const float* __restrict__ lng,
                                             const float* __restrict__ lnb,
                                             float* __restrict__ h2) {
    int b = blockIdx.x, tid = threadIdx.x;
    float v[4];
    float s = 0.f, s2 = 0.f;
#pragma unroll
    for (int j = 0; j < 4; ++j) {
        int nidx = tid + 256 * j;
        float x = g1[b * H4 + nidx];
        v[j] = x;
        s += x; s2 += x * x;
    }
#pragma unroll
    for (int off = 32; off > 0; off >>= 1) {
        s  += __shfl_down(s, off);
        s2 += __shfl_down(s2, off);
    }
    __shared__ float ls[4], ls2[4], smu, srs;
    int wave = tid >> 6;
    if ((tid & 63) == 0) { ls[wave] = s; ls2[wave] = s2; }
    __syncthreads();
    if (tid == 0) {
        float S  = ls[0] + ls[1] + ls[2] + ls[3];
        float S2 = ls2[0] + ls2[1] + ls2[2] + ls2[3];
        float mu = S / (float)H4;
        float var = S2 / (float)H4 - mu * mu;
        smu = mu;
        srs = rsqrtf(var + 1e-5f);
    }
    __syncthreads();
    float mu = smu, rs = srs;
#pragma unroll
    for (int j = 0; j < 4; ++j) {
        int nidx = tid + 256 * j;
        h2[b * H4 + nidx] = (v[j] - mu) * rs * lng[nidx] + lnb[nidx];
    }
}

// ---------------- launch ----------------
extern "C" void kernel_launch(void* const* d_in, const int* in_sizes, int n_in,
                              void* d_out, int out_size, void* d_ws, size_t ws_size,
                              hipStream_t stream) {
    (void)in_sizes; (void)n_in; (void)out_size;
    const int*   tags  = (const int*)d_in[0];
    const float* fc    = (const float*)d_in[1];
    const float* ln_g  = (const float*)d_in[2];
    const float* ln_b  = (const float*)d_in[3];
    const float* w1    = (const float*)d_in[4];
    const float* b1    = (const float*)d_in[5];
    const float* ln2_g = (const float*)d_in[6];
    const float* ln2_b = (const float*)d_in[7];
    const float* we1   = (const float*)d_in[8];
    const float* be1   = (const float*)d_in[9];
    const float* we2   = (const float*)d_in[10];
    const float* be2   = (const float*)d_in[11];
    const float* wd1   = (const float*)d_in[12];
    const float* bd1   = (const float*)d_in[13];
    const float* wd2   = (const float*)d_in[14];
    const float* bd2   = (const float*)d_in[15];

    float* out = (float*)d_out;
    float* y   = out;                              // 64*20001
    float* enc = out + (size_t)BATCH * NT1;        // 64*256
    float* dec = enc + BATCH * HD;                 // 64*20001

    char* ws = (char*)d_ws;
    size_t off = 0;
    int*   counts = (int*)(ws + off);   off += (size_t)BATCH * NUM_TAGS * 4;  // 5.12 MB
    float* stats  = (float*)(ws + off); off += 64 * 8 * 2 * 4;
    float* g1     = (float*)(ws + off); off += (size_t)BATCH * H4 * 4;
    float* h2     = (float*)(ws + off); off += (size_t)BATCH * H4 * 4;
    float* g2     = (float*)(ws + off); off += (size_t)BATCH * H4 * 4;
    float* dd     = (float*)(ws + off); off += (size_t)BATCH * H4 * 4;
    float* arena  = (float*)(ws + off);
    size_t avail  = (ws_size > off) ? (ws_size - off) : 0;

    // split-K tiers (ws_size constant across calls -> deterministic)
    const size_t MB = 1024 * 1024;
    int KS1, KS5;
    if (avail >= 45 * MB)      { KS1 = 125; KS5 = 8; }   // arenas 32.8 / 41.4 MB
    else if (avail >= 33 * MB) { KS1 = 125; KS5 = 4; }
    else if (avail >= 17 * MB) { KS1 = 63;  KS5 = 4; }
    else                       { KS1 = 63;  KS5 = 2; }
    int kpb5 = H4 / KS5;
    (void)KS1;

    hipMemsetAsync(counts, 0, (size_t)BATCH * NUM_TAGS * 4, stream);
    k_scatter<<<32, 256, 0, stream>>>(tags, counts);
    k_ln1_stats<<<dim3(8, 64), 256, 0, stream>>>(counts, stats);
    k_ln1_apply<<<dim3(8, 64), 256, 0, stream>>>(counts, fc, ln_g, ln_b, stats, y);

    // GEMM1: yn[64,20000] @ w1[1:,1024]; fc-column folded into reduce as rank-1
    k_gemm<0><<<dim3(4, 125), 256, 0, stream>>>(y + 1, NT1, w1 + H4, H4, arena, H4, 160);
    k_reduce<true><<<dim3(4, 64), 256, 0, stream>>>(arena, 125, b1, w1, fc, g1, H4, H4);
    k_ln2<<<64, 256, 0, stream>>>(g1, ln2_g, ln2_b, h2);

    // GEMM2: h2 @ we1[1024,1024]
    k_gemm<0><<<dim3(4, 32), 256, 0, stream>>>(h2, H4, we1, H4, arena, H4, 32);
    k_reduce<true><<<dim3(4, 64), 256, 0, stream>>>(arena, 32, be1, nullptr, nullptr, g2, H4, H4);

    // GEMM3: g2 @ we2[1024,256]
    k_gemm<0><<<dim3(1, 32), 256, 0, stream>>>(g2, H4, we2, HD, arena, HD, 32);
    k_reduce<false><<<dim3(1, 64), 256, 0, stream>>>(arena, 32, be2, nullptr, nullptr, enc, HD, HD);

    // GEMM4: enc @ wd1[256,1024]
    k_gemm<0><<<dim3(4, 16), 256, 0, stream>>>(enc, HD, wd1, H4, arena, H4, 16);
    k_reduce<true><<<dim3(4, 64), 256, 0, stream>>>(arena, 16, bd1, nullptr, nullptr, dd, H4, H4);

    // GEMM5: dd @ wd2[1024,20001]  (odd ldw -> PATH 1)
    k_gemm<1><<<dim3(79, KS5), 256, 0, stream>>>(dd, H4, wd2, NT1, arena, NT1, kpb5);
    k_reduce<false><<<dim3(79, 64), 256, 0, stream>>>(arena, KS5, bd2, nullptr, nullptr, dec, NT1, NT1);
}